// Round 1
// baseline (141.099 us; speedup 1.0000x reference)
//
#include <hip/hip_runtime.h>
#include <hip/hip_bf16.h>

#define N_NODES 8192
#define F_IN 256
#define F_OUT 128

typedef __attribute__((ext_vector_type(4))) float f32x4;
typedef __attribute__((ext_vector_type(8))) short bf16x8;
typedef __attribute__((ext_vector_type(4))) unsigned short u16x4;

static __device__ __forceinline__ unsigned short f2bf(float f) {
    union { float f; unsigned int u; } v; v.f = f;
    unsigned int r = v.u + 0x7FFFu + ((v.u >> 16) & 1u);
    return (unsigned short)(r >> 16);
}

// Kernel 1: support^T[f][n] = sum_k X[n][k] * W[k][f]   (fp32 accum -> bf16 out)
// Block: 256 threads, 32 rows x 128 cols. Grid: 256.
__global__ __launch_bounds__(256) void support_kernel(
        const float* __restrict__ X, const float* __restrict__ W,
        unsigned short* __restrict__ supT) {
    __shared__ float Xs[32][68];     // +4 pad: conflict-free, 16B-aligned rows
    __shared__ float Ws[64][128];
    const int t = threadIdx.x;
    const int n0 = blockIdx.x * 32;
    const int tc = t & 31;           // col group: cols tc*4 .. tc*4+3
    const int tr = t >> 5;           // 0..7 row group: rows tr*4 .. tr*4+3
    float acc[4][4];
    #pragma unroll
    for (int i = 0; i < 4; ++i)
        #pragma unroll
        for (int j = 0; j < 4; ++j) acc[i][j] = 0.f;

    for (int k0 = 0; k0 < F_IN; k0 += 64) {
        __syncthreads();
        {   // stage X tile 32x64: 8 floats/thread
            const int r = t >> 3, kc = (t & 7) * 8;
            const float* src = X + (size_t)(n0 + r) * F_IN + k0 + kc;
            f32x4 v0 = *(const f32x4*)src;
            f32x4 v1 = *(const f32x4*)(src + 4);
            *(f32x4*)&Xs[r][kc]     = v0;
            *(f32x4*)&Xs[r][kc + 4] = v1;
        }
        {   // stage W tile 64x128: 32 floats/thread
            const int col = t & 127, kb = t >> 7;
            #pragma unroll
            for (int i = 0; i < 32; ++i) {
                const int k = kb + i * 2;
                Ws[k][col] = W[(size_t)(k0 + k) * F_OUT + col];
            }
        }
        __syncthreads();
        #pragma unroll 8
        for (int k = 0; k < 64; ++k) {
            const f32x4 b = *(const f32x4*)&Ws[k][tc * 4];
            float a[4];
            #pragma unroll
            for (int i = 0; i < 4; ++i) a[i] = Xs[tr * 4 + i][k];
            #pragma unroll
            for (int i = 0; i < 4; ++i) {
                acc[i][0] += a[i] * b.x; acc[i][1] += a[i] * b.y;
                acc[i][2] += a[i] * b.z; acc[i][3] += a[i] * b.w;
            }
        }
    }
    #pragma unroll
    for (int j = 0; j < 4; ++j) {
        const int col = tc * 4 + j;
        #pragma unroll
        for (int i = 0; i < 4; ++i) {
            supT[(size_t)col * N_NODES + n0 + tr * 4 + i] = f2bf(acc[i][j]);
        }
    }
}

// Kernel 2: out[n][f] = sum_k adj[n][k] * support[k][f] + bias[f]
// BM=16, BK=64, full N=128. Grid 512 (2 blocks/CU). 4 waves, each 16x32 slice.
__global__ __launch_bounds__(256) void gcn_kernel(
        const float* __restrict__ adj, const unsigned short* __restrict__ supT,
        const float* __restrict__ bias, float* __restrict__ out) {
    __shared__ unsigned short As[16][72];    // adj tile, bf16, row stride 144B
    __shared__ unsigned short Bs[128][72];   // supT tile, bf16
    const int t = threadIdx.x;
    const int n0 = blockIdx.x * 16;
    const int w = t >> 6;            // wave 0..3 -> cols w*32
    const int l = t & 63;

    // staging assignments
    const int a_row = t >> 4;        // 0..15
    const int a_kc  = (t & 15) * 4;  // 0,4,...,60
    const int b_col = t >> 1;        // 0..127
    const int b_kc  = (t & 1) * 32;  // 0 or 32

    const float* a_src = adj + (size_t)(n0 + a_row) * N_NODES + a_kc;
    const unsigned short* b_src = supT + (size_t)b_col * N_NODES + b_kc;

    f32x4 acc0 = {0.f, 0.f, 0.f, 0.f};
    f32x4 acc1 = {0.f, 0.f, 0.f, 0.f};

    // prologue: tile 0 into registers
    f32x4 ar  = *(const f32x4*)a_src;
    f32x4 br0 = *(const f32x4*)(b_src);
    f32x4 br1 = *(const f32x4*)(b_src + 8);
    f32x4 br2 = *(const f32x4*)(b_src + 16);
    f32x4 br3 = *(const f32x4*)(b_src + 24);

    const int NT = N_NODES / 64;     // 128 K-tiles
    for (int tt = 0; tt < NT; ++tt) {
        // commit staged regs to LDS
        u16x4 a4;
        a4.x = f2bf(ar.x); a4.y = f2bf(ar.y); a4.z = f2bf(ar.z); a4.w = f2bf(ar.w);
        *(u16x4*)&As[a_row][a_kc]      = a4;
        *(f32x4*)&Bs[b_col][b_kc + 0]  = br0;
        *(f32x4*)&Bs[b_col][b_kc + 8]  = br1;
        *(f32x4*)&Bs[b_col][b_kc + 16] = br2;
        *(f32x4*)&Bs[b_col][b_kc + 24] = br3;
        __syncthreads();
        // issue next tile's global loads (latency hides under MFMA + sibling block)
        if (tt + 1 < NT) {
            const int k0n = (tt + 1) * 64;
            ar  = *(const f32x4*)(a_src + k0n);
            br0 = *(const f32x4*)(b_src + k0n);
            br1 = *(const f32x4*)(b_src + k0n + 8);
            br2 = *(const f32x4*)(b_src + k0n + 16);
            br3 = *(const f32x4*)(b_src + k0n + 24);
        }
        #pragma unroll
        for (int ks = 0; ks < 2; ++ks) {
            const int ko = ks * 32 + (l >> 4) * 8;
            bf16x8 af  = *(const bf16x8*)&As[l & 15][ko];
            bf16x8 bf0 = *(const bf16x8*)&Bs[w * 32 + (l & 15)][ko];
            bf16x8 bf1 = *(const bf16x8*)&Bs[w * 32 + 16 + (l & 15)][ko];
            acc0 = __builtin_amdgcn_mfma_f32_16x16x32_bf16(af, bf0, acc0, 0, 0, 0);
            acc1 = __builtin_amdgcn_mfma_f32_16x16x32_bf16(af, bf1, acc1, 0, 0, 0);
        }
        __syncthreads();
    }
    // epilogue: C/D layout col=l&15, row=(l>>4)*4+i   [m89-verified]
    const int col0 = w * 32 + (l & 15);
    const int rb = (l >> 4) * 4;
    const float bv0 = bias[col0], bv1 = bias[col0 + 16];
    #pragma unroll
    for (int i = 0; i < 4; ++i) {
        const int row = n0 + rb + i;
        out[(size_t)row * F_OUT + col0]      = acc0[i] + bv0;
        out[(size_t)row * F_OUT + col0 + 16] = acc1[i] + bv1;
    }
}

extern "C" void kernel_launch(void* const* d_in, const int* in_sizes, int n_in,
                              void* d_out, int out_size, void* d_ws, size_t ws_size,
                              hipStream_t stream) {
    const float* input  = (const float*)d_in[0];
    const float* adj    = (const float*)d_in[1];
    const float* weight = (const float*)d_in[2];
    const float* bias   = (const float*)d_in[3];
    float* out = (float*)d_out;
    unsigned short* supT = (unsigned short*)d_ws;   // [F_OUT][N_NODES] bf16 = 2 MiB

    support_kernel<<<N_NODES / 32, 256, 0, stream>>>(input, weight, supT);
    gcn_kernel<<<N_NODES / 16, 256, 0, stream>>>(adj, supT, bias, out);
}